// Round 1
// baseline (659.022 us; speedup 1.0000x reference)
//
#include <hip/hip_runtime.h>

typedef _Float16 half8 __attribute__((ext_vector_type(8)));
typedef _Float16 half4 __attribute__((ext_vector_type(4)));
typedef float f32x4 __attribute__((ext_vector_type(4)));

#define WPAD 264      // hbuf row stride (f16): 528 B = 33*16, b128-aligned, conflict-benign
#define NPB 64        // points per block
#define THREADS 256   // 4 waves; wave owns 64 features x all 64 points
#define INV2PI 0.15915494309189535f
#define W0SCALE (30.0f * INV2PI)
#define SMEM_BYTES (NPB * WPAD * 2 + (192 + 256) * 4)   // 35584 B -> 3+ blocks/CU (LDS-wise)

// Repack W1..W4 fp32 [256x256] row-major -> f16 chunk-major [kc][n][kl] (kc=k/32, kl=k%32),
// PRESCALED by 1/(2*pi) so the epilogue sine is a bare v_sin_f32 (input in revolutions).
__global__ void convert_weights(const float* __restrict__ W1, const float* __restrict__ W2,
                                const float* __restrict__ W3, const float* __restrict__ W4,
                                _Float16* __restrict__ Wc) {
    int tid = blockIdx.x * 256 + threadIdx.x;      // 0 .. 262143
    int l   = tid >> 16;
    int rem = tid & 65535;
    int n = rem >> 8, k = rem & 255;
    const float* W = (l == 0) ? W1 : (l == 1) ? W2 : (l == 2) ? W3 : W4;
    int kc = k >> 5, kl = k & 31;
    Wc[l * 65536 + kc * 8192 + n * 32 + kl] = (_Float16)(W[rem] * INV2PI);
}

__launch_bounds__(THREADS, 3)   // >=3 waves/SIMD -> reg cap 170; target 3 blocks/CU
__global__ void siren_fused(const float* __restrict__ xyt,
                            const float* __restrict__ W0,
                            const float* __restrict__ b0,
                            const _Float16* __restrict__ Wc,
                            const float* __restrict__ b1,
                            const float* __restrict__ b2,
                            const float* __restrict__ b3,
                            const float* __restrict__ b4,
                            const float* __restrict__ Wf,
                            const float* __restrict__ bfin,
                            float* __restrict__ out)
{
    extern __shared__ _Float16 smem[];
    _Float16* hbuf = smem;                           // [NPB][WPAD] f16, 33792 B
    float* xs   = (float*)(smem + NPB * WPAD);       // 192 f32
    float* wf_s = xs + 192;                          // 256 f32

    const int tid  = threadIdx.x;
    const int lane = tid & 63;
    const int wv   = tid >> 6;       // wave 0..3; owns features [wv*64, wv*64+64)
    const int l15  = lane & 15;
    const int l4   = lane >> 4;
    const int gm0  = blockIdx.x * NPB;

    if (tid < 192) xs[tid] = xyt[gm0 * 3 + tid];
    wf_s[tid] = Wf[tid];             // exactly 256 threads
    __syncthreads();

    // ---- layer 0: h = sin(30*(x @ W0^T + b0)); prescaled -> bare v_sin; packed b64 writes ----
    {
        const int fg = lane;          // features 4*lane .. 4*lane+3
        const int p0 = wv * 16;       // this wave's 16 points
        float w[4][3], bb[4];
        #pragma unroll
        for (int c = 0; c < 4; ++c) {
            const int n = fg * 4 + c;
            w[c][0] = W0[n * 3 + 0] * W0SCALE;
            w[c][1] = W0[n * 3 + 1] * W0SCALE;
            w[c][2] = W0[n * 3 + 2] * W0SCALE;
            bb[c]   = b0[n] * W0SCALE;
        }
        #pragma unroll 4
        for (int p = 0; p < 16; ++p) {
            const float x0 = xs[(p0 + p) * 3], x1 = xs[(p0 + p) * 3 + 1], x2 = xs[(p0 + p) * 3 + 2];
            half4 hv;
            #pragma unroll
            for (int c = 0; c < 4; ++c) {
                float z = fmaf(w[c][0], x0, fmaf(w[c][1], x1, fmaf(w[c][2], x2, bb[c])));
                hv[c] = (_Float16)__builtin_amdgcn_sinf(z);   // z in revolutions
            }
            *(half4*)&hbuf[(p0 + p) * WPAD + fg * 4] = hv;
        }
    }

    // lane's byte-invariant A offset within any 16KB K-chunk (i adds 16 rows = 512 f16)
    const int arow = (wv * 64 + l15) * 32 + l4 * 8;

    // ---- 4 hidden layers: D[feat][pt] = W' h^T (MFMA f16), sin via v_sin, bias in acc init ----
    #pragma unroll
    for (int l = 0; l < 4; ++l) {
        const float* bl = (l == 0) ? b1 : (l == 1) ? b2 : (l == 2) ? b3 : b4;
        const _Float16* wl = Wc + l * 65536;

        // A-ring prologue (kc=0,1): issued BEFORE the barrier (latency hidden by it)
        half8 areg[2][4];
        #pragma unroll
        for (int c = 0; c < 2; ++c)
            #pragma unroll
            for (int i = 0; i < 4; ++i)
                areg[c][i] = *(const half8*)&wl[c * 8192 + arow + i * 512];

        f32x4 acc[4][4];
        #pragma unroll
        for (int i = 0; i < 4; ++i) {
            f32x4 bb = *(const f32x4*)&bl[wv * 64 + i * 16 + l4 * 4];
            bb *= INV2PI;
            #pragma unroll
            for (int j = 0; j < 4; ++j)
                acc[i][j] = bb;       // bias folded into accumulator init (prescaled)
        }

        __syncthreads();   // hbuf from previous layer stable

        #pragma unroll
        for (int kc = 0; kc < 8; ++kc) {
            // prefetch A chunk kc+2 (covers ~2 MFMA phases of L2 latency)
            half8 anext[4];
            if (kc < 6) {
                #pragma unroll
                for (int i = 0; i < 4; ++i)
                    anext[i] = *(const half8*)&wl[(kc + 2) * 8192 + arow + i * 512];
            }
            // B from LDS: 4 b128 reads feed 16 MFMAs (2x the reuse of the 8-wave version)
            half8 bfr[4];
            #pragma unroll
            for (int j = 0; j < 4; ++j)
                bfr[j] = *(const half8*)&hbuf[(j * 16 + l15) * WPAD + kc * 32 + l4 * 8];
            __builtin_amdgcn_s_setprio(1);
            #pragma unroll
            for (int i = 0; i < 4; ++i)
                #pragma unroll
                for (int j = 0; j < 4; ++j)
                    acc[i][j] = __builtin_amdgcn_mfma_f32_16x16x32_f16(
                        areg[kc & 1][i], bfr[j], acc[i][j], 0, 0, 0);
            __builtin_amdgcn_s_setprio(0);
            if (kc < 6) {
                #pragma unroll
                for (int i = 0; i < 4; ++i)
                    areg[kc & 1][i] = anext[i];
            }
        }

        // Epilogue sin into REGISTERS before the barrier: overlaps lagging waves' MFMAs;
        // only the packed b64 stores remain in the serialized inter-barrier window.
        half4 hv[4][4];
        #pragma unroll
        for (int i = 0; i < 4; ++i)
            #pragma unroll
            for (int j = 0; j < 4; ++j)
                #pragma unroll
                for (int r = 0; r < 4; ++r)
                    hv[i][j][r] = (_Float16)__builtin_amdgcn_sinf(acc[i][j][r]);

        __syncthreads();   // all waves' B-reads done -> safe to overwrite hbuf

        // C-layout: col = point (lane&15), feature = wv*64 + i*16 + l4*4 + r.
        #pragma unroll
        for (int i = 0; i < 4; ++i)
            #pragma unroll
            for (int j = 0; j < 4; ++j)
                *(half4*)&hbuf[(j * 16 + l15) * WPAD + wv * 64 + i * 16 + l4 * 4] = hv[i][j];
        // next layer's first barrier publishes these writes
    }

    __syncthreads();   // final hbuf visible

    // ---- final layer: out[m] = h[m,:] . Wf + bf, 4 lanes per point ----
    {
        const int m = tid >> 2, q = tid & 3;     // m in 0..63
        const _Float16* hrow = &hbuf[m * WPAD + q * 64];
        float sum = 0.f;
        #pragma unroll
        for (int i = 0; i < 8; ++i) {
            half8 hv = *(const half8*)&hrow[i * 8];
            const int nb = q * 64 + i * 8;
            #pragma unroll
            for (int j = 0; j < 8; ++j)
                sum = fmaf((float)hv[j], wf_s[nb + j], sum);
        }
        sum += __shfl_down(sum, 2);
        sum += __shfl_down(sum, 1);
        if (q == 0) out[gm0 + m] = sum + bfin[0];
    }
}

extern "C" void kernel_launch(void* const* d_in, const int* in_sizes, int n_in,
                              void* d_out, int out_size, void* d_ws, size_t ws_size,
                              hipStream_t stream) {
    const float* xyt = (const float*)d_in[0];
    const float* W0  = (const float*)d_in[1];
    const float* b0  = (const float*)d_in[2];
    const float* W1  = (const float*)d_in[3];
    const float* b1  = (const float*)d_in[4];
    const float* W2  = (const float*)d_in[5];
    const float* b2  = (const float*)d_in[6];
    const float* W3  = (const float*)d_in[7];
    const float* b3  = (const float*)d_in[8];
    const float* W4  = (const float*)d_in[9];
    const float* b4  = (const float*)d_in[10];
    const float* Wf  = (const float*)d_in[11];
    const float* bf  = (const float*)d_in[12];
    float* out = (float*)d_out;
    _Float16* Wc = (_Float16*)d_ws;    // 4 * 65536 f16 = 512 KB

    hipFuncSetAttribute((const void*)siren_fused,
                        hipFuncAttributeMaxDynamicSharedMemorySize, SMEM_BYTES);

    convert_weights<<<1024, 256, 0, stream>>>(W1, W2, W3, W4, Wc);

    const int N = in_sizes[0] / 3;     // 1048576
    siren_fused<<<N / NPB, THREADS, SMEM_BYTES, stream>>>(
        xyt, W0, b0, Wc, b1, b2, b3, b4, Wf, bf, out);
}

// Round 2
// 653.715 us; speedup vs baseline: 1.0081x; 1.0081x over previous
//
#include <hip/hip_runtime.h>

typedef _Float16 half8 __attribute__((ext_vector_type(8)));
typedef _Float16 half4 __attribute__((ext_vector_type(4)));
typedef float f32x4 __attribute__((ext_vector_type(4)));

#define WPAD 264      // hbuf row stride (f16): 528 B = 33*16, b128-aligned, conflict-benign
#define NPB 96        // points per block
#define THREADS 512   // 8 waves; wave owns 32 features x all 96 points
#define INV2PI 0.15915494309189535f
#define W0SCALE (30.0f * INV2PI)
#define SMEM_BYTES (NPB * WPAD * 2 + (288 + 256) * 4)   // 52864 B -> 3 blocks/CU

// Repack W1..W4 fp32 [256x256] row-major -> f16 chunk-major [kc][n][kl] (kc=k/32, kl=k%32),
// PRESCALED by 1/(2*pi) so the epilogue sine is a bare v_sin_f32 (input in revolutions).
__global__ void convert_weights(const float* __restrict__ W1, const float* __restrict__ W2,
                                const float* __restrict__ W3, const float* __restrict__ W4,
                                _Float16* __restrict__ Wc) {
    int tid = blockIdx.x * 256 + threadIdx.x;      // 0 .. 262143
    int l   = tid >> 16;
    int rem = tid & 65535;
    int n = rem >> 8, k = rem & 255;
    const float* W = (l == 0) ? W1 : (l == 1) ? W2 : (l == 2) ? W3 : W4;
    int kc = k >> 5, kl = k & 31;
    Wc[l * 65536 + kc * 8192 + n * 32 + kl] = (_Float16)(W[rem] * INV2PI);
}

__launch_bounds__(THREADS, 6)   // 6 waves/SIMD target -> reg cap 85 -> 3 blocks/CU
__global__ void siren_fused(const float* __restrict__ xyt,
                            const float* __restrict__ W0,
                            const float* __restrict__ b0,
                            const _Float16* __restrict__ Wc,
                            const float* __restrict__ b1,
                            const float* __restrict__ b2,
                            const float* __restrict__ b3,
                            const float* __restrict__ b4,
                            const float* __restrict__ Wf,
                            const float* __restrict__ bfin,
                            float* __restrict__ out,
                            int npts)
{
    extern __shared__ _Float16 smem[];
    _Float16* hbuf = smem;                           // [NPB][WPAD] f16, 50688 B
    float* xs   = (float*)(smem + NPB * WPAD);       // 288 f32
    float* wf_s = xs + 288;                          // 256 f32

    const int tid  = threadIdx.x;
    const int lane = tid & 63;
    const int wv   = tid >> 6;       // wave 0..7; owns features [wv*32, wv*32+32)
    const int l15  = lane & 15;
    const int l4   = lane >> 4;
    const int gm0  = blockIdx.x * NPB;
    const int nv   = min(NPB, npts - gm0);   // valid points in this block (tail = 64)

    if (tid < nv * 3) xs[tid] = xyt[gm0 * 3 + tid];
    if (tid < 256) wf_s[tid] = Wf[tid];
    __syncthreads();

    // ---- layer 0: h = sin(30*(x @ W0^T + b0)); prescaled -> bare v_sin; packed b64 writes ----
    {
        const int fg = lane;          // features 4*lane .. 4*lane+3
        const int p0 = wv * 12;       // this wave's 12 points
        float w[4][3], bb[4];
        #pragma unroll
        for (int c = 0; c < 4; ++c) {
            const int n = fg * 4 + c;
            w[c][0] = W0[n * 3 + 0] * W0SCALE;
            w[c][1] = W0[n * 3 + 1] * W0SCALE;
            w[c][2] = W0[n * 3 + 2] * W0SCALE;
            bb[c]   = b0[n] * W0SCALE;
        }
        #pragma unroll 4
        for (int p = 0; p < 12; ++p) {
            const float x0 = xs[(p0 + p) * 3], x1 = xs[(p0 + p) * 3 + 1], x2 = xs[(p0 + p) * 3 + 2];
            half4 hv;
            #pragma unroll
            for (int c = 0; c < 4; ++c) {
                float z = fmaf(w[c][0], x0, fmaf(w[c][1], x1, fmaf(w[c][2], x2, bb[c])));
                hv[c] = (_Float16)__builtin_amdgcn_sinf(z);   // z in revolutions
            }
            *(half4*)&hbuf[(p0 + p) * WPAD + fg * 4] = hv;
        }
    }

    // lane's byte-invariant A offset within any 16KB K-chunk (i adds 16 rows = 512 f16)
    const int arow = (wv * 32 + l15) * 32 + l4 * 8;

    // ---- 4 hidden layers: D[feat][pt] = W' h^T (MFMA f16), sin via v_sin, bias in acc init ----
    #pragma unroll
    for (int l = 0; l < 4; ++l) {
        const float* bl = (l == 0) ? b1 : (l == 1) ? b2 : (l == 2) ? b3 : b4;
        const _Float16* wl = Wc + l * 65536;

        f32x4 acc[2][6];
        #pragma unroll
        for (int i = 0; i < 2; ++i) {
            f32x4 bb = *(const f32x4*)&bl[wv * 32 + i * 16 + l4 * 4];
            bb *= INV2PI;
            #pragma unroll
            for (int j = 0; j < 6; ++j)
                acc[i][j] = bb;       // bias folded into accumulator init (prescaled)
        }

        __syncthreads();   // hbuf from previous layer stable

        #pragma unroll
        for (int kc = 0; kc < 8; ++kc) {
            // A for this K-chunk: L2-resident, latency hidden by 6 waves/SIMD of TLP
            half8 a0 = *(const half8*)&wl[kc * 8192 + arow];
            half8 a1 = *(const half8*)&wl[kc * 8192 + arow + 512];
            // B from LDS in two half-groups of 3 point-tiles to cap live regs
            #pragma unroll
            for (int g = 0; g < 2; ++g) {
                half8 bfr[3];
                #pragma unroll
                for (int j = 0; j < 3; ++j)
                    bfr[j] = *(const half8*)&hbuf[((g * 3 + j) * 16 + l15) * WPAD + kc * 32 + l4 * 8];
                __builtin_amdgcn_s_setprio(1);
                #pragma unroll
                for (int j = 0; j < 3; ++j) {
                    acc[0][g * 3 + j] = __builtin_amdgcn_mfma_f32_16x16x32_f16(
                        a0, bfr[j], acc[0][g * 3 + j], 0, 0, 0);
                    acc[1][g * 3 + j] = __builtin_amdgcn_mfma_f32_16x16x32_f16(
                        a1, bfr[j], acc[1][g * 3 + j], 0, 0, 0);
                }
                __builtin_amdgcn_s_setprio(0);
            }
        }

        // Epilogue sin into REGISTERS before the barrier: overlaps lagging waves' MFMAs;
        // only the packed b64 stores remain in the serialized inter-barrier window.
        half4 hv[2][6];
        #pragma unroll
        for (int i = 0; i < 2; ++i)
            #pragma unroll
            for (int j = 0; j < 6; ++j)
                #pragma unroll
                for (int r = 0; r < 4; ++r)
                    hv[i][j][r] = (_Float16)__builtin_amdgcn_sinf(acc[i][j][r]);

        __syncthreads();   // all waves' B-reads done -> safe to overwrite hbuf

        // C-layout: col = point (lane&15), feature = wv*32 + i*16 + l4*4 + r.
        #pragma unroll
        for (int i = 0; i < 2; ++i)
            #pragma unroll
            for (int j = 0; j < 6; ++j)
                *(half4*)&hbuf[(j * 16 + l15) * WPAD + wv * 32 + i * 16 + l4 * 4] = hv[i][j];
        // next layer's first barrier publishes these writes
    }

    __syncthreads();   // final hbuf visible

    // ---- final layer: out[m] = h[m,:] . Wf + bf, 4 lanes per point ----
    {
        const int m = tid >> 2, q = tid & 3;     // m in 0..127; only m<96 exist
        if (m < nv) {
            const _Float16* hrow = &hbuf[m * WPAD + q * 64];
            float sum = 0.f;
            #pragma unroll
            for (int i = 0; i < 8; ++i) {
                half8 hv = *(const half8*)&hrow[i * 8];
                const int nb = q * 64 + i * 8;
                #pragma unroll
                for (int j = 0; j < 8; ++j)
                    sum = fmaf((float)hv[j], wf_s[nb + j], sum);
            }
            sum += __shfl_down(sum, 2);
            sum += __shfl_down(sum, 1);
            if (q == 0) out[gm0 + m] = sum + bfin[0];
        }
    }
}

extern "C" void kernel_launch(void* const* d_in, const int* in_sizes, int n_in,
                              void* d_out, int out_size, void* d_ws, size_t ws_size,
                              hipStream_t stream) {
    const float* xyt = (const float*)d_in[0];
    const float* W0  = (const float*)d_in[1];
    const float* b0  = (const float*)d_in[2];
    const float* W1  = (const float*)d_in[3];
    const float* b1  = (const float*)d_in[4];
    const float* W2  = (const float*)d_in[5];
    const float* b2  = (const float*)d_in[6];
    const float* W3  = (const float*)d_in[7];
    const float* b3  = (const float*)d_in[8];
    const float* W4  = (const float*)d_in[9];
    const float* b4  = (const float*)d_in[10];
    const float* Wf  = (const float*)d_in[11];
    const float* bf  = (const float*)d_in[12];
    float* out = (float*)d_out;
    _Float16* Wc = (_Float16*)d_ws;    // 4 * 65536 f16 = 512 KB

    hipFuncSetAttribute((const void*)siren_fused,
                        hipFuncAttributeMaxDynamicSharedMemorySize, SMEM_BYTES);

    convert_weights<<<1024, 256, 0, stream>>>(W1, W2, W3, W4, Wc);

    const int N = in_sizes[0] / 3;     // 1048576
    const int grid = (N + NPB - 1) / NPB;   // 10923, last block has 64 valid points
    siren_fused<<<grid, THREADS, SMEM_BYTES, stream>>>(
        xyt, W0, b0, Wc, b1, b2, b3, b4, Wf, bf, out, N);
}

// Round 3
// 606.186 us; speedup vs baseline: 1.0872x; 1.0784x over previous
//
#include <hip/hip_runtime.h>

typedef _Float16 half8 __attribute__((ext_vector_type(8)));
typedef _Float16 half4 __attribute__((ext_vector_type(4)));
typedef float f32x4 __attribute__((ext_vector_type(4)));

#define NPB 128       // points per block
#define THREADS 512   // 8 waves; wave owns 32 features x all 128 points
#define INV2PI 0.15915494309189535f
#define W0SCALE (30.0f * INV2PI)
#define SMEM_BYTES (NPB * 256 * 2 + (384 + 256) * 4)   // 68096 B -> 2 blocks/CU

// hbuf: [128 rows][256 f16], 512 B rows, XOR unit-swizzle per row to kill bank
// conflicts. f16 index for (row=point, col=feature): swizzle XORs 16B-unit index
// (f16 bits 3-5) with row&7. Applied identically on EVERY hbuf read and write.
__device__ __forceinline__ int hswz(int row, int col) {
    return (row << 8) + (col ^ ((row & 7) << 3));
}

// Repack W1..W4 fp32 [256x256] row-major -> f16 chunk-major [kc][n][kl] (kc=k/32, kl=k%32),
// PRESCALED by 1/(2*pi) so the epilogue sine is a bare v_sin_f32 (input in revolutions).
__global__ void convert_weights(const float* __restrict__ W1, const float* __restrict__ W2,
                                const float* __restrict__ W3, const float* __restrict__ W4,
                                _Float16* __restrict__ Wc) {
    int tid = blockIdx.x * 256 + threadIdx.x;      // 0 .. 262143
    int l   = tid >> 16;
    int rem = tid & 65535;
    int n = rem >> 8, k = rem & 255;
    const float* W = (l == 0) ? W1 : (l == 1) ? W2 : (l == 2) ? W3 : W4;
    int kc = k >> 5, kl = k & 31;
    Wc[l * 65536 + kc * 8192 + n * 32 + kl] = (_Float16)(W[rem] * INV2PI);
}

__launch_bounds__(THREADS, 4)
__global__ void siren_fused(const float* __restrict__ xyt,
                            const float* __restrict__ W0,
                            const float* __restrict__ b0,
                            const _Float16* __restrict__ Wc,
                            const float* __restrict__ b1,
                            const float* __restrict__ b2,
                            const float* __restrict__ b3,
                            const float* __restrict__ b4,
                            const float* __restrict__ Wf,
                            const float* __restrict__ bfin,
                            float* __restrict__ out)
{
    extern __shared__ _Float16 smem[];
    _Float16* hbuf = smem;                           // [128][256] f16 swizzled, 65536 B
    float* xs   = (float*)(smem + NPB * 256);        // 384 f32
    float* wf_s = xs + 384;                          // 256 f32

    const int tid  = threadIdx.x;
    const int lane = tid & 63;
    const int wv   = tid >> 6;       // wave 0..7; owns features [wv*32, wv*32+32)
    const int l15  = lane & 15;
    const int l4   = lane >> 4;
    const int gm0  = blockIdx.x * NPB;

    if (tid < 384) xs[tid] = xyt[gm0 * 3 + tid];
    if (tid < 256) wf_s[tid] = Wf[tid];
    __syncthreads();

    // ---- layer 0: h = sin(30*(x @ W0^T + b0)); prescaled -> bare v_sin; packed b64 writes ----
    {
        const int fg = lane;          // features 4*lane .. 4*lane+3
        const int p0 = wv * 16;       // this wave's 16 points
        float w[4][3], bb[4];
        #pragma unroll
        for (int c = 0; c < 4; ++c) {
            const int n = fg * 4 + c;
            w[c][0] = W0[n * 3 + 0] * W0SCALE;
            w[c][1] = W0[n * 3 + 1] * W0SCALE;
            w[c][2] = W0[n * 3 + 2] * W0SCALE;
            bb[c]   = b0[n] * W0SCALE;
        }
        #pragma unroll 4
        for (int p = 0; p < 16; ++p) {
            const float x0 = xs[(p0 + p) * 3], x1 = xs[(p0 + p) * 3 + 1], x2 = xs[(p0 + p) * 3 + 2];
            half4 hv;
            #pragma unroll
            for (int c = 0; c < 4; ++c) {
                float z = fmaf(w[c][0], x0, fmaf(w[c][1], x1, fmaf(w[c][2], x2, bb[c])));
                hv[c] = (_Float16)__builtin_amdgcn_sinf(z);   // z in revolutions
            }
            *(half4*)&hbuf[hswz(p0 + p, fg * 4)] = hv;
        }
    }

    // lane's byte-invariant A offset within any 16KB K-chunk (i adds 16 rows = 512 f16)
    const int arow = (wv * 32 + l15) * 32 + l4 * 8;

    // ---- 4 hidden layers: D[feat][pt] = W' h^T (MFMA f16), sin via v_sin, bias in acc init ----
    #pragma unroll
    for (int l = 0; l < 4; ++l) {
        const float* bl = (l == 0) ? b1 : (l == 1) ? b2 : (l == 2) ? b3 : b4;
        const _Float16* wl = Wc + l * 65536;

        // A-ring prologue (kc=0,1): issued BEFORE the barrier (latency hidden by it)
        half8 areg[2][2];
        #pragma unroll
        for (int c = 0; c < 2; ++c)
            #pragma unroll
            for (int i = 0; i < 2; ++i)
                areg[c][i] = *(const half8*)&wl[c * 8192 + arow + i * 512];

        f32x4 acc[2][8];
        #pragma unroll
        for (int i = 0; i < 2; ++i) {
            f32x4 bb = *(const f32x4*)&bl[wv * 32 + i * 16 + l4 * 4];
            bb *= INV2PI;
            #pragma unroll
            for (int j = 0; j < 8; ++j)
                acc[i][j] = bb;       // bias folded into accumulator init (prescaled)
        }

        __syncthreads();   // hbuf from previous layer stable

        #pragma unroll
        for (int kc = 0; kc < 8; ++kc) {
            // prefetch A chunk kc+2 (covers ~2 MFMA phases of L2 latency)
            half8 anext[2];
            if (kc < 6) {
                #pragma unroll
                for (int i = 0; i < 2; ++i)
                    anext[i] = *(const half8*)&wl[(kc + 2) * 8192 + arow + i * 512];
            }
            // B from LDS in-loop, two half-groups to cap live regs; swizzled addresses
            #pragma unroll
            for (int g = 0; g < 2; ++g) {
                half8 bfr[4];
                #pragma unroll
                for (int j = 0; j < 4; ++j)
                    bfr[j] = *(const half8*)&hbuf[hswz((g * 4 + j) * 16 + l15, kc * 32 + l4 * 8)];
                #pragma unroll
                for (int i = 0; i < 2; ++i)
                    #pragma unroll
                    for (int j = 0; j < 4; ++j)
                        acc[i][g * 4 + j] = __builtin_amdgcn_mfma_f32_16x16x32_f16(
                            areg[kc & 1][i], bfr[j], acc[i][g * 4 + j], 0, 0, 0);
            }
            if (kc < 6) { areg[kc & 1][0] = anext[0]; areg[kc & 1][1] = anext[1]; }
        }

        __syncthreads();   // all waves' B-reads done -> safe to overwrite hbuf

        // Epilogue: C-layout col = point (lane&15), feature = wv*32 + i*16 + l4*4 + r.
        // acc already holds (W h + b)/(2pi): one v_sin per value, packed half4 store.
        #pragma unroll
        for (int i = 0; i < 2; ++i)
            #pragma unroll
            for (int j = 0; j < 8; ++j) {
                half4 hv;
                #pragma unroll
                for (int r = 0; r < 4; ++r)
                    hv[r] = (_Float16)__builtin_amdgcn_sinf(acc[i][j][r]);
                *(half4*)&hbuf[hswz(j * 16 + l15, wv * 32 + i * 16 + l4 * 4)] = hv;
            }
        // next layer's first barrier publishes these writes
    }

    __syncthreads();   // final hbuf visible

    // ---- final layer: out[m] = h[m,:] . Wf + bf, 4 lanes per point ----
    {
        const int m = tid >> 2, q = tid & 3;
        float sum = 0.f;
        #pragma unroll
        for (int i = 0; i < 8; ++i) {
            half8 hv = *(const half8*)&hbuf[hswz(m, q * 64 + i * 8)];
            const int nb = q * 64 + i * 8;
            #pragma unroll
            for (int j = 0; j < 8; ++j)
                sum = fmaf((float)hv[j], wf_s[nb + j], sum);
        }
        sum += __shfl_down(sum, 2);
        sum += __shfl_down(sum, 1);
        if (q == 0) out[gm0 + m] = sum + bfin[0];
    }
}

extern "C" void kernel_launch(void* const* d_in, const int* in_sizes, int n_in,
                              void* d_out, int out_size, void* d_ws, size_t ws_size,
                              hipStream_t stream) {
    const float* xyt = (const float*)d_in[0];
    const float* W0  = (const float*)d_in[1];
    const float* b0  = (const float*)d_in[2];
    const float* W1  = (const float*)d_in[3];
    const float* b1  = (const float*)d_in[4];
    const float* W2  = (const float*)d_in[5];
    const float* b2  = (const float*)d_in[6];
    const float* W3  = (const float*)d_in[7];
    const float* b3  = (const float*)d_in[8];
    const float* W4  = (const float*)d_in[9];
    const float* b4  = (const float*)d_in[10];
    const float* Wf  = (const float*)d_in[11];
    const float* bf  = (const float*)d_in[12];
    float* out = (float*)d_out;
    _Float16* Wc = (_Float16*)d_ws;    // 4 * 65536 f16 = 512 KB

    hipFuncSetAttribute((const void*)siren_fused,
                        hipFuncAttributeMaxDynamicSharedMemorySize, SMEM_BYTES);

    convert_weights<<<1024, 256, 0, stream>>>(W1, W2, W3, W4, Wc);

    const int N = in_sizes[0] / 3;     // 1048576
    siren_fused<<<N / NPB, THREADS, SMEM_BYTES, stream>>>(
        xyt, W0, b0, Wc, b1, b2, b3, b4, Wf, bf, out);
}